// Round 1
// baseline (67.725 us; speedup 1.0000x reference)
//
#include <hip/hip_runtime.h>
#include <math.h>

// BroadcastConv (max-plus conv): out[b,o,y,x] = max_{c,i,j} img[b,c,y+i-2,x+j-2] + kern[o,c,4-i,4-j]
// B=4, C=16, O=16, H=W=64, k=5x5, pad=2 with -inf.
//
// R5 (fused single kernel):
//  - pad_kernel eliminated: halo rows staged into LDS per block with inline -inf
//    bounds handling (no 1.18 MB global round trip, one launch instead of two).
//  - o-split reduced 4->2 (grid 64 y x 2 og x 4 b = 512 blocks, 8 o per block):
//    halves redundant window loads, 2 blocks/CU = 16 waves/CU.
//  - c-split across 8 waves (2 c/wave) kept; per-wave acc[8], LDS max-reduce tail.
//  - taps read from LDS as stride-1 ds_read_b32 (conflict-free: 2-way lane
//    aliasing on 32 banks is free), adds as v_pk_add_f32, maxes fuse to v_max3.

#define NEG_INF (-__builtin_inff())
#define ROWW   68              // padded row width: 64 + 2*2
#define CPLANE (5 * ROWW)      // 340 floats per channel (5 halo rows)
#define STAGE_N (16 * CPLANE)  // 5440 floats = 21.76 KB

typedef float f32x2 __attribute__((ext_vector_type(2)));

__global__ __launch_bounds__(512, 4) void bconv_fused(
        const float* __restrict__ img,
        const float* __restrict__ kern,
        float* __restrict__ out) {
    const int tid = threadIdx.x;
    const int x   = tid & 63;                                  // lane = output x
    const int w   = __builtin_amdgcn_readfirstlane(tid >> 6);  // wave id 0..7, UNIFORM
    const int y   = blockIdx.x;
    const int og  = blockIdx.y;            // 0..1 -> o_base = og*8
    const int b   = blockIdx.z;

    __shared__ float tap[STAGE_N];         // [c][row 0..4][col 0..67], col-2 = img col
    __shared__ float red[8][8][64];        // [wave][o][x]

    // ---- stage rows y-2..y+2 of all 16 channels, cols -2..65 (bounds -> -inf) ----
    const float* __restrict__ imgb = img + (b << 14);   // b * 16 * 4096
    for (int k = tid; k < STAGE_N; k += 512) {
        const int c   = k / CPLANE;
        const int rem = k - c * CPLANE;
        const int r   = rem / ROWW;
        const int col = rem - r * ROWW - 2;    // img col, -2..65
        const int row = y + r - 2;             // img row, -2..65
        const bool ok = ((unsigned)row < 64u) & ((unsigned)col < 64u);
        const int idx = ok ? ((c << 12) + (row << 6) + col) : 0;
        tap[k] = ok ? imgb[idx] : NEG_INF;
    }
    __syncthreads();

    // ---- compute: each wave covers channels {2w, 2w+1} for all 8 o of this block ----
    const int c0     = w * 2;
    const int o_base = og * 8;

    float acc[8];
#pragma unroll
    for (int o = 0; o < 8; ++o) acc[o] = NEG_INF;

#pragma unroll
    for (int cc = 0; cc < 2; ++cc) {
        const int c = c0 + cc;
        const float* tp = &tap[c * CPLANE + x];

        float v[5][5];
#pragma unroll
        for (int i = 0; i < 5; ++i)
#pragma unroll
            for (int j = 0; j < 5; ++j)
                v[i][j] = tp[i * ROWW + j];   // stride-1 across lanes: conflict-free

        // tap (i,j) pairs with kern[o][c][4-i][4-j] = kp[24 - 5i - j] (double flip)
#pragma unroll
        for (int o = 0; o < 8; ++o) {
            const float* __restrict__ kp = kern + ((o_base + o) * 16 + c) * 25;  // uniform -> s_load
#pragma unroll
            for (int g = 0; g < 5; ++g) {
                const int kb = 24 - g * 5;
                f32x2 a01 = (f32x2){v[g][0], v[g][1]} + (f32x2){kp[kb],     kp[kb - 1]};
                f32x2 a23 = (f32x2){v[g][2], v[g][3]} + (f32x2){kp[kb - 2], kp[kb - 3]};
                float a4  = v[g][4] + kp[kb - 4];
                float m01  = fmaxf(a01.x, a01.y);                       // v_max
                float m234 = fmaxf(fmaxf(a23.x, a23.y), a4);            // v_max3
                acc[o] = fmaxf(acc[o], fmaxf(m01, m234));               // v_max3
            }
        }
    }

    // ---- cross-wave max reduction (each wave covered 2 of 16 channels) ----
#pragma unroll
    for (int o = 0; o < 8; ++o) red[w][o][x] = acc[o];
    __syncthreads();

    const int oo = tid >> 6;               // one (o, x) output per thread
    float r = red[0][oo][x];
#pragma unroll
    for (int ww = 1; ww < 8; ++ww) r = fmaxf(r, red[ww][oo][x]);
    out[((b * 16 + o_base + oo) << 12) + (y << 6) + x] = r;
}

extern "C" void kernel_launch(void* const* d_in, const int* in_sizes, int n_in,
                              void* d_out, int out_size, void* d_ws, size_t ws_size,
                              hipStream_t stream) {
    const float* img  = (const float*)d_in[0];   // (4,16,64,64)
    const float* kern = (const float*)d_in[1];   // (16,16,5,5)
    float* out = (float*)d_out;                  // (4,16,64,64)
    (void)in_sizes; (void)n_in; (void)out_size; (void)d_ws; (void)ws_size;

    dim3 grid(64, 2, 4);   // y, o/8, b -> 512 blocks, 2/CU, 16 waves/CU
    hipLaunchKernelGGL(bconv_fused, grid, dim3(512), 0, stream, img, kern, out);
}